// Round 10
// baseline (211.058 us; speedup 1.0000x reference)
//
#include <hip/hip_runtime.h>
#include <stdint.h>

// SuperpointGenerator: per-batch voxel id -> count -> top-256 by (count desc, id asc)
// -> labels 0..255 (else -1); if U<=256, label = dense rank by ascending id.
//
// R7/R8 measured: global RMW atomics on gfx950 execute memory-side (~64B fabric
// round trip each, scope-independent) -> count without global atomics:
//   - central 28^3 cube (98.5% of N(0,1)/0.2 points) counted in per-block LDS
//     u16-packed histograms, flushed with plain stores (phist),
//   - ring 28^3..64^3 (~1.5%): direct global atomicAdd into gtab[64^3],
//   - outside +-32 (~never, exact): tiny per-batch CAS hash table otab.
// k_compact sums phist for central voxels (gtab central stays ZERO) and scans
// gtab for ring voxels + otab for overflow, appending 50-bit priority keys
// (count<<32 | ~u, u=id^0x80000000) with one global atomic per block.
// k_select: ONE kernel, one block per batch: 5-pass MSB radix select (10-bit
// digits, LDS hist + parallel suffix scan), LDS collect, rank-sort, label write
// (winner slots get ~rank >= 0xFFFFFF00; decode low >= 0xFFF00000).
// XCD affinity: blocks of batch b have blockIdx%8 == b%8 (L2 heuristic only).

namespace {
constexpr int B_ = 16;
constexpr int N_ = 262144;            // 2^18 points per batch
constexpr int LOGN_ = 18;
constexpr int K_ = 256;
constexpr int G_ = 262144;            // 64^3 direct slots per batch
constexpr int OC_ = 4096;             // overflow CAS slots per batch
constexpr int CKSTR_ = G_ + OC_;      // ckeys stride per batch
constexpr int DIM_ = 28, HDIM_ = 14;  // central LDS cube: voxels [-14,14)
constexpr int BINS_ = DIM_ * DIM_ * DIM_;   // 21952
constexpr int WORDS_ = BINS_ / 2;           // 10976 packed u32 words
constexpr int BPB_ = 16;              // build blocks per batch (256 total = 1/CU)
constexpr int PPB_ = N_ / BPB_;       // 16384 points per build block
constexpr int CCH_ = (WORDS_ + 255) / 256;  // 43 central compact chunks
constexpr int RCH_ = G_ / 1024;             // 256 ring chunks (1024 slots each)
constexpr int OCH_ = OC_ / 256;             // 16 overflow chunks
constexpr int NCH_ = CCH_ + RCH_ + OCH_;    // 315 chunks per batch
typedef unsigned long long ull;
}

// bid -> (batch, chunk): batch = (bid&7) + 8*((bid>>3)&1)  => batch % 8 == bid % 8
__device__ __forceinline__ void swz(int bid, int& b, int& chunk) {
    b = (bid & 7) + (((bid >> 3) & 1) << 3);
    chunk = bid >> 4;
}

__device__ __forceinline__ unsigned ohash(int id) {
    return ((unsigned)id * 2654435761u) >> 20;       // 12-bit slot in otab
}

// Block-aggregated append of valid keys to ckeys[b] (one global atomic / block).
// blockDim == 256 (4 waves).
__device__ __forceinline__ void append_keys(bool valid, ull key, int b,
                                            ull* __restrict__ ckeys,
                                            unsigned* __restrict__ csize,
                                            unsigned* woff, unsigned* pbase) {
    ull mask = __ballot(valid);
    int lane = threadIdx.x & 63, wave = threadIdx.x >> 6;
    if (lane == 0) woff[wave] = (unsigned)__popcll(mask);
    __syncthreads();
    if (threadIdx.x == 0) {
        unsigned tot = 0;
        for (int w2 = 0; w2 < 4; ++w2) { unsigned c = woff[w2]; woff[w2] = tot; tot += c; }
        *pbase = tot ? atomicAdd(&csize[b], tot) : 0u;
    }
    __syncthreads();
    if (valid) {
        unsigned pos = *pbase + woff[wave]
                     + (unsigned)__popcll(mask & ((1ull << lane) - 1ull));
        ckeys[(size_t)b * CKSTR_ + pos] = key;
    }
    __syncthreads();                                 // woff/pbase reusable after
}

__global__ void __launch_bounds__(1024)
k_build(const float* __restrict__ coords, unsigned* __restrict__ gtab,
        ull* __restrict__ otab, int* __restrict__ pslot,
        unsigned* __restrict__ phist) {
    int b, chunk;
    swz(blockIdx.x, b, chunk);                       // grid == 256 (16 x 16)
    __shared__ unsigned lh[WORDS_];                  // 43.9 KB packed u16 pairs
    for (int w = threadIdx.x; w < WORDS_; w += 1024) lh[w] = 0u;
    __syncthreads();
    for (int r = 0; r < PPB_ / 1024; ++r) {
        int p = chunk * PPB_ + r * 1024 + (int)threadIdx.x;
        size_t i = ((size_t)b << LOGN_) + (size_t)p;
        const float* c = coords + i * 3;
        // Must match jnp.floor(c / 0.2f) bit-exactly: IEEE fp32 division.
        float cx = __builtin_nontemporal_load(c + 0);
        float cy = __builtin_nontemporal_load(c + 1);
        float cz = __builtin_nontemporal_load(c + 2);
        int vx = (int)floorf(cx / 0.2f);
        int vy = (int)floorf(cy / 0.2f);
        int vz = (int)floorf(cz / 0.2f);
        int ax = vx + HDIM_, ay = vy + HDIM_, az = vz + HDIM_;
        if ((unsigned)ax < (unsigned)DIM_ && (unsigned)ay < (unsigned)DIM_ &&
            (unsigned)az < (unsigned)DIM_) {
            int lidx = (ax * DIM_ + ay) * DIM_ + az;
            atomicAdd(&lh[lidx >> 1], 1u << ((lidx & 1) << 4));   // LDS, packed u16
            int gidx = ((vx + 32) << 12) | ((vy + 32) << 6) | (vz + 32);
            __builtin_nontemporal_store(gidx, &pslot[i]);
        } else if ((unsigned)(vx + 32) < 64u && (unsigned)(vy + 32) < 64u &&
                   (unsigned)(vz + 32) < 64u) {
            int gidx = ((vx + 32) << 12) | ((vy + 32) << 6) | (vz + 32);
            atomicAdd(&gtab[((size_t)b << 18) | gidx], 1u);       // ~1.5% of points
            __builtin_nontemporal_store(gidx, &pslot[i]);
        } else {                                     // essentially never; exact
            int id = vx * 10000 + vy * 100 + vz;
            unsigned u = (unsigned)id ^ 0x80000000u;
            unsigned s = ohash(id);
            ull* t = otab + (size_t)b * OC_;
            for (;;) {
                ull cur = t[s];
                if (cur == 0ull) {
                    ull prev = atomicCAS(&t[s], 0ull, ((ull)u << 32) | 1ull);
                    if (prev == 0ull) break;
                    cur = prev;
                }
                if ((unsigned)(cur >> 32) == u) { atomicAdd(&t[s], 1ull); break; }
                s = (s + 1) & (OC_ - 1);
            }
            __builtin_nontemporal_store((int)(0x80000000u | s), &pslot[i]);
        }
    }
    __syncthreads();
    unsigned* ph = phist + (size_t)(b * BPB_ + chunk) * WORDS_;
    for (int w = threadIdx.x; w < WORDS_; w += 1024)
        __builtin_nontemporal_store(lh[w], &ph[w]);  // plain coalesced flush
}

// Append nonzero voxels' priority keys. chunks: [0,CCH_) central-from-phist,
// [CCH_, CCH_+RCH_) ring-from-gtab (1024 slots/chunk), rest otab.
__global__ void __launch_bounds__(256)
k_compact(const unsigned* __restrict__ phist, const unsigned* __restrict__ gtab,
          const ull* __restrict__ otab, ull* __restrict__ ckeys,
          unsigned* __restrict__ csize) {
    int b, chunk;
    swz(blockIdx.x, b, chunk);                       // grid == 16 * NCH_
    __shared__ unsigned woff[4];
    __shared__ unsigned pbase;
    if (chunk < CCH_) {
        int w = chunk * 256 + (int)threadIdx.x;
        unsigned s0 = 0, s1 = 0;
        if (w < WORDS_) {
            const unsigned* ph = phist + (size_t)b * BPB_ * WORDS_ + w;
            for (int blk = 0; blk < BPB_; ++blk)
                { unsigned v = ph[(size_t)blk * WORDS_]; s0 += v & 0xFFFFu; s1 += v >> 16; }
        }
        int bin0 = 2 * (chunk * 256 + (int)threadIdx.x);
        int ax = bin0 / (DIM_ * DIM_);
        int r2 = bin0 % (DIM_ * DIM_);
        int ay = r2 / DIM_, az = r2 % DIM_;
        int vx = ax - HDIM_, vy = ay - HDIM_, vz = az - HDIM_;
        int id0 = vx * 10000 + vy * 100 + vz;        // bin0 and bin0+1 differ by vz+1
        ull key0 = ((ull)s0 << 32) | (ull)(~((unsigned)id0 ^ 0x80000000u));
        ull key1 = ((ull)s1 << 32) | (ull)(~((unsigned)(id0 + 1) ^ 0x80000000u));
        append_keys(w < WORDS_ && s0 != 0, key0, b, ckeys, csize, woff, &pbase);
        append_keys(w < WORDS_ && s1 != 0, key1, b, ckeys, csize, woff, &pbase);
    } else if (chunk < CCH_ + RCH_) {
        int base = (chunk - CCH_) * 1024 + 4 * (int)threadIdx.x;
        uint4 cv = *(const uint4*)&gtab[((size_t)b << 18) | base];
        unsigned cnt[4] = {cv.x, cv.y, cv.z, cv.w};
        for (int j = 0; j < 4; ++j) {
            int f = base + j;
            int vx = (f >> 12) - 32, vy = ((f >> 6) & 63) - 32, vz = (f & 63) - 32;
            int id = vx * 10000 + vy * 100 + vz;
            ull key = ((ull)cnt[j] << 32) | (ull)(~((unsigned)id ^ 0x80000000u));
            append_keys(cnt[j] != 0u, key, b, ckeys, csize, woff, &pbase);
        }
    } else {
        int s = (chunk - CCH_ - RCH_) * 256 + (int)threadIdx.x;
        ull e = otab[(size_t)b * OC_ + s];
        ull key = ((ull)(unsigned)e << 32) | (ull)(~(unsigned)(e >> 32));
        append_keys(e != 0ull, key, b, ckeys, csize, woff, &pbase);
    }
}

// One block per batch: full radix select + collect + rank + label write.
__global__ void __launch_bounds__(1024)
k_select(const unsigned* __restrict__ csize, const ull* __restrict__ ckeys,
         unsigned* __restrict__ gtab, ull* __restrict__ otab) {
    int b = blockIdx.x;                              // 16 blocks; b -> XCD b%8
    int U = (int)csize[b];
    const ull* keys = ckeys + (size_t)b * CKSTR_;
    int t = threadIdx.x;

    __shared__ unsigned hist[1024];
    __shared__ unsigned ss[1024];
    __shared__ ull skeys[K_];
    __shared__ ull spfx;
    __shared__ unsigned srem;
    __shared__ int ssel;

    ull thr = 0ull;
    if (U > K_) {
        ull prefix = 0ull;
        unsigned rem = (unsigned)K_;
        for (int sh = 40; sh >= 0; sh -= 10) {
            hist[t] = 0u;
            __syncthreads();
            ull hi = ~0ull << (sh + 10);
            for (int i = t; i < U; i += 1024) {
                ull k = keys[i];
                if ((k & hi) == prefix)
                    atomicAdd(&hist[(unsigned)(k >> sh) & 1023u], 1u);
            }
            __syncthreads();
            unsigned cc = hist[t];
            ss[t] = cc;
            __syncthreads();
            for (int off = 1; off < 1024; off <<= 1) {   // inclusive suffix sum
                unsigned v = (t + off < 1024) ? ss[t + off] : 0u;
                __syncthreads();
                ss[t] += v;
                __syncthreads();
            }
            unsigned Sincl = ss[t], Sexcl = Sincl - cc;
            if (Sexcl < rem && rem <= Sincl) {           // unique t (cc > 0)
                spfx = prefix | ((ull)t << sh);
                srem = rem - Sexcl;
            }
            __syncthreads();
            prefix = spfx;
            rem = srem;
            __syncthreads();
        }
        thr = prefix;                                    // exactly K_ keys >= thr
    }

    if (t == 0) ssel = 0;
    __syncthreads();
    for (int i = t; i < U; i += 1024) {
        ull k = keys[i];
        if (U <= K_ || k >= thr) { int p = atomicAdd(&ssel, 1); skeys[p] = k; }
    }
    __syncthreads();
    int S = ssel;                                        // ==256 when U>K, else ==U

    if (t < S) {
        // U>K: rank by full key desc (count desc, id asc). U<=K: id asc only.
        ull k = skeys[t];
        int rank = 0;
        if (U > K_) {
            for (int j = 0; j < S; ++j) rank += (skeys[j] > k);
        } else {
            unsigned kl = (unsigned)k;
            for (int j = 0; j < S; ++j) rank += ((unsigned)skeys[j] > kl);
        }
        unsigned u = ~((unsigned)k);
        int id = (int)(u ^ 0x80000000u);
        int idp = id + 32 * 10000 + 32 * 100 + 32;   // (vx+32)*1e4+(vy+32)*1e2+(vz+32)
        bool direct = false; int gidx = 0;
        if (idp >= 0) {
            int a = idp / 10000, r2 = idp % 10000, bb = r2 / 100, cc2 = r2 % 100;
            if (a < 64 && bb < 64 && cc2 < 64) { direct = true; gidx = (a << 12) | (bb << 6) | cc2; }
        }
        if (direct) {
            gtab[((size_t)b << 18) | gidx] = ~(unsigned)rank;
        } else {
            unsigned s2 = ohash(id);
            ull* tb = otab + (size_t)b * OC_;
            while ((unsigned)(tb[s2] >> 32) != u) s2 = (s2 + 1) & (OC_ - 1);
            tb[s2] = ((ull)u << 32) | (ull)(~(unsigned)rank);
        }
    }
}

__global__ void k_label(const int* __restrict__ pslot, const unsigned* __restrict__ gtab,
                        const ull* __restrict__ otab, int* __restrict__ out) {
    int b, chunk;
    swz(blockIdx.x, b, chunk);                       // grid == B_*N_/256
    int p = chunk * 256 + (int)threadIdx.x;
    size_t i = ((size_t)b << LOGN_) + (size_t)p;
    int s = __builtin_nontemporal_load(&pslot[i]);
    unsigned low;
    if (s >= 0) low = gtab[((size_t)b << 18) | s];
    else        low = (unsigned)otab[(size_t)b * OC_ + (s & (OC_ - 1))];
    __builtin_nontemporal_store((low >= 0xFFF00000u) ? (int)(~low) : -1, &out[i]);
}

extern "C" void kernel_launch(void* const* d_in, const int* in_sizes, int n_in,
                              void* d_out, int out_size, void* d_ws, size_t ws_size,
                              hipStream_t stream) {
    const float* coords = (const float*)d_in[0];
    int* out = (int*)d_out;

    // Workspace layout (~78 MB). gtab|otab|csize contiguous -> one memset.
    char* w = (char*)d_ws;
    size_t off = 0;
    unsigned* gtab = (unsigned*)(w + off);      off += (size_t)B_ * G_ * 4;   // 16 MB
    ull* otab = (ull*)(w + off);                off += (size_t)B_ * OC_ * 8;  // 512 KB
    unsigned* csize = (unsigned*)(w + off);     off += 64;                    // 64 B
    size_t zbytes = off;
    int* pslot = (int*)(w + off);               off += (size_t)B_ * N_ * 4;   // 16 MB
    ull* ckeys = (ull*)(w + off);               off += (size_t)B_ * CKSTR_ * 8; // 34 MB
    unsigned* phist = (unsigned*)(w + off);     off += (size_t)B_ * BPB_ * WORDS_ * 4; // 11.2 MB

    hipMemsetAsync(gtab, 0, zbytes, stream);
    k_build<<<B_ * BPB_, 1024, 0, stream>>>(coords, gtab, otab, pslot, phist);
    k_compact<<<B_ * NCH_, 256, 0, stream>>>(phist, gtab, otab, ckeys, csize);
    k_select<<<B_, 1024, 0, stream>>>(csize, ckeys, gtab, otab);
    k_label<<<B_ * N_ / 256, 256, 0, stream>>>(pslot, gtab, otab, out);
}

// Round 11
// 170.299 us; speedup vs baseline: 1.2393x; 1.2393x over previous
//
#include <hip/hip_runtime.h>
#include <stdint.h>

// SuperpointGenerator: per-batch voxel id -> count -> top-256 by (count desc, id asc)
// -> labels 0..255 (else -1); if U<=256, label = dense rank by ascending id.
//
// Measured on gfx950 (R1..R10): any global RMW atomic is memory-side (~64B
// fabric round trip, ~0.1us same-address serialized, scope-independent).
// So this version uses ZERO global atomics on hot paths:
//   - central 28^3 cube (98.5% of N(0,1)/0.2 points) counted in per-block LDS
//     u16-packed histograms, flushed with plain stores (phist),
//   - ring 28^3..64^3 (~1.5%): direct global atomicAdd into gtab[64^3] (sparse),
//   - outside +-32 (~never, exact): tiny per-batch CAS hash table otab,
//   - k_compact: one block per fixed-capacity SEGMENT of ckeys; block prefix
//     scan gives positions; segment length stored with a plain store. NO atomics.
//   - k_select (one block per batch): prefix segments, dense-copy to dkeys,
//     5-pass MSB radix select (10-bit digits, LDS hist + parallel suffix scan),
//     LDS collect, rank-sort, winner labels written as ~rank (>= 0xFFFFFF00;
//     decode low >= 0xFFF00000; counts <= 2^18 never collide).
// XCD affinity: blocks of batch b have blockIdx%8 == b%8 (L2 heuristic only).

namespace {
constexpr int B_ = 16;
constexpr int N_ = 262144;            // 2^18 points per batch
constexpr int LOGN_ = 18;
constexpr int K_ = 256;
constexpr int G_ = 262144;            // 64^3 direct slots per batch
constexpr int OC_ = 4096;             // overflow CAS slots per batch
constexpr int DIM_ = 28, HDIM_ = 14;  // central LDS cube: voxels [-14,14)
constexpr int BINS_ = DIM_ * DIM_ * DIM_;   // 21952
constexpr int WORDS_ = BINS_ / 2;           // 10976 packed u32 words
constexpr int BPB_ = 16;              // build blocks per batch (256 total = 1/CU)
constexpr int PPB_ = N_ / BPB_;       // 16384 points per build block
// compact segments per batch: 43 central (cap 512) + 128 ring (cap 2048) + 4 otab (cap 1024)
constexpr int CSEG_ = 43, RSEG_ = 128, OSEG_ = 4;
constexpr int NSEG_ = CSEG_ + RSEG_ + OSEG_;           // 175
constexpr int RBASE_ = CSEG_ * 512;                    // 22016
constexpr int OBASE_ = RBASE_ + RSEG_ * 2048;          // 284160
constexpr int CKSTR_ = OBASE_ + OSEG_ * 1024;          // 288256 keys per batch
typedef unsigned long long ull;
}

// bid -> (batch, chunk): batch = (bid&7) + 8*((bid>>3)&1)  => batch % 8 == bid % 8
__device__ __forceinline__ void swz(int bid, int& b, int& chunk) {
    b = (bid & 7) + (((bid >> 3) & 1) << 3);
    chunk = bid >> 4;
}

__device__ __forceinline__ unsigned ohash(int id) {
    return ((unsigned)id * 2654435761u) >> 20;       // 12-bit slot in otab
}

__device__ __forceinline__ int segbase(int s) {
    if (s < CSEG_) return s * 512;
    if (s < CSEG_ + RSEG_) return RBASE_ + (s - CSEG_) * 2048;
    return OBASE_ + (s - CSEG_ - RSEG_) * 1024;
}

__device__ __forceinline__ ull mkkey(unsigned cnt, int id) {
    return ((ull)cnt << 32) | (ull)(~((unsigned)id ^ 0x80000000u));
}

__global__ void __launch_bounds__(1024)
k_build(const float* __restrict__ coords, unsigned* __restrict__ gtab,
        ull* __restrict__ otab, int* __restrict__ pslot,
        unsigned* __restrict__ phist) {
    int b, chunk;
    swz(blockIdx.x, b, chunk);                       // grid == 256 (16 x 16)
    __shared__ unsigned lh[WORDS_];                  // 43.9 KB packed u16 pairs
    for (int w = threadIdx.x; w < WORDS_; w += 1024) lh[w] = 0u;
    __syncthreads();
    for (int r = 0; r < PPB_ / 1024; ++r) {
        int p = chunk * PPB_ + r * 1024 + (int)threadIdx.x;
        size_t i = ((size_t)b << LOGN_) + (size_t)p;
        const float* c = coords + i * 3;
        // Must match jnp.floor(c / 0.2f) bit-exactly: IEEE fp32 division.
        float cx = __builtin_nontemporal_load(c + 0);
        float cy = __builtin_nontemporal_load(c + 1);
        float cz = __builtin_nontemporal_load(c + 2);
        int vx = (int)floorf(cx / 0.2f);
        int vy = (int)floorf(cy / 0.2f);
        int vz = (int)floorf(cz / 0.2f);
        int ax = vx + HDIM_, ay = vy + HDIM_, az = vz + HDIM_;
        if ((unsigned)ax < (unsigned)DIM_ && (unsigned)ay < (unsigned)DIM_ &&
            (unsigned)az < (unsigned)DIM_) {
            int lidx = (ax * DIM_ + ay) * DIM_ + az;
            atomicAdd(&lh[lidx >> 1], 1u << ((lidx & 1) << 4));   // LDS, packed u16
            int gidx = ((vx + 32) << 12) | ((vy + 32) << 6) | (vz + 32);
            __builtin_nontemporal_store(gidx, &pslot[i]);
        } else if ((unsigned)(vx + 32) < 64u && (unsigned)(vy + 32) < 64u &&
                   (unsigned)(vz + 32) < 64u) {
            int gidx = ((vx + 32) << 12) | ((vy + 32) << 6) | (vz + 32);
            atomicAdd(&gtab[((size_t)b << 18) | gidx], 1u);       // ~1.5% of points
            __builtin_nontemporal_store(gidx, &pslot[i]);
        } else {                                     // essentially never; exact
            int id = vx * 10000 + vy * 100 + vz;
            unsigned u = (unsigned)id ^ 0x80000000u;
            unsigned s = ohash(id);
            ull* t = otab + (size_t)b * OC_;
            for (;;) {
                ull cur = t[s];
                if (cur == 0ull) {
                    ull prev = atomicCAS(&t[s], 0ull, ((ull)u << 32) | 1ull);
                    if (prev == 0ull) break;
                    cur = prev;
                }
                if ((unsigned)(cur >> 32) == u) { atomicAdd(&t[s], 1ull); break; }
                s = (s + 1) & (OC_ - 1);
            }
            __builtin_nontemporal_store((int)(0x80000000u | s), &pslot[i]);
        }
    }
    __syncthreads();
    unsigned* ph = phist + (size_t)(b * BPB_ + chunk) * WORDS_;
    for (int w = threadIdx.x; w < WORDS_; w += 1024)
        __builtin_nontemporal_store(lh[w], &ph[w]);  // plain coalesced flush
}

// One block = one segment. Compute keys, block-prefix positions, plain stores.
// Segment chunk: [0,43) central-from-phist (2 bins/thread), [43,171) ring-from-
// gtab (8 slots/thread), [171,175) otab (4 slots/thread). ZERO global atomics.
__global__ void __launch_bounds__(256)
k_compact(const unsigned* __restrict__ phist, const unsigned* __restrict__ gtab,
          const ull* __restrict__ otab, ull* __restrict__ ckeys,
          unsigned* __restrict__ segcnt) {
    int b, chunk;
    swz(blockIdx.x, b, chunk);                       // grid == 16 * NSEG_
    int nv = 0;

    // --- per-thread item discovery (all static-indexed; rule-#20 safe) ---
    unsigned s0 = 0, s1 = 0; int id0 = 0;            // central
    unsigned rc[8]; int rbase0 = 0;                  // ring counts
    ull e0 = 0, e1 = 0, e2 = 0, e3 = 0;              // otab entries
    if (chunk < CSEG_) {
        int w = chunk * 256 + (int)threadIdx.x;
        if (w < WORDS_) {
            const unsigned* ph = phist + (size_t)b * BPB_ * WORDS_ + w;
            #pragma unroll
            for (int blk = 0; blk < BPB_; ++blk) {
                unsigned v = ph[(size_t)blk * WORDS_];
                s0 += v & 0xFFFFu; s1 += v >> 16;
            }
            int bin0 = 2 * w;
            int ax = bin0 / (DIM_ * DIM_);
            int r2 = bin0 % (DIM_ * DIM_);
            int ay = r2 / DIM_, az = r2 % DIM_;
            id0 = (ax - HDIM_) * 10000 + (ay - HDIM_) * 100 + (az - HDIM_);
        }
        nv = (s0 != 0) + (s1 != 0);
    } else if (chunk < CSEG_ + RSEG_) {
        rbase0 = (chunk - CSEG_) * 2048 + (int)threadIdx.x * 8;
        const unsigned* gt = gtab + (((size_t)b << 18) + rbase0);
        uint4 c0 = *(const uint4*)gt;
        uint4 c1 = *(const uint4*)(gt + 4);
        rc[0] = c0.x; rc[1] = c0.y; rc[2] = c0.z; rc[3] = c0.w;
        rc[4] = c1.x; rc[5] = c1.y; rc[6] = c1.z; rc[7] = c1.w;
        #pragma unroll
        for (int j = 0; j < 8; ++j) nv += (rc[j] != 0u);
    } else {
        int s = (chunk - CSEG_ - RSEG_) * 1024 + (int)threadIdx.x * 4;
        const ull* ot = otab + (size_t)b * OC_ + s;
        e0 = ot[0]; e1 = ot[1]; e2 = ot[2]; e3 = ot[3];
        nv = (e0 != 0) + (e1 != 0) + (e2 != 0) + (e3 != 0);
    }

    // --- block-wide exclusive prefix of nv (shfl within wave, LDS across) ---
    int lane = threadIdx.x & 63, wave = threadIdx.x >> 6;
    unsigned pre = (unsigned)nv;
    #pragma unroll
    for (int o = 1; o < 64; o <<= 1) {
        unsigned v = __shfl_up(pre, o);
        if (lane >= o) pre += v;
    }
    __shared__ unsigned wtot[4], wbase[4];
    if (lane == 63) wtot[wave] = pre;
    __syncthreads();
    if (threadIdx.x == 0) {
        unsigned acc = 0;
        for (int w2 = 0; w2 < 4; ++w2) { wbase[w2] = acc; acc += wtot[w2]; }
        segcnt[b * NSEG_ + chunk] = acc;             // plain store, no atomic
    }
    __syncthreads();
    unsigned pos = wbase[wave] + pre - (unsigned)nv;

    // --- unrolled conditional writes (recompute keys; no indexed reg array) ---
    ull* dst = ckeys + (size_t)b * CKSTR_ + segbase(chunk);
    if (chunk < CSEG_) {
        if (s0) dst[pos++] = mkkey(s0, id0);
        if (s1) dst[pos]   = mkkey(s1, id0 + 1);
    } else if (chunk < CSEG_ + RSEG_) {
        #pragma unroll
        for (int j = 0; j < 8; ++j) {
            if (rc[j]) {
                int f = rbase0 + j;
                int id = ((f >> 12) - 32) * 10000 + (((f >> 6) & 63) - 32) * 100
                       + ((f & 63) - 32);
                dst[pos++] = mkkey(rc[j], id);
            }
        }
    } else {
        if (e0) dst[pos++] = ((ull)(unsigned)e0 << 32) | (ull)(~(unsigned)(e0 >> 32));
        if (e1) dst[pos++] = ((ull)(unsigned)e1 << 32) | (ull)(~(unsigned)(e1 >> 32));
        if (e2) dst[pos++] = ((ull)(unsigned)e2 << 32) | (ull)(~(unsigned)(e2 >> 32));
        if (e3) dst[pos]   = ((ull)(unsigned)e3 << 32) | (ull)(~(unsigned)(e3 >> 32));
    }
}

// One block per batch: dense-copy segments, radix select, collect, rank, write.
__global__ void __launch_bounds__(1024)
k_select(const unsigned* __restrict__ segcnt, const ull* __restrict__ ckeys,
         ull* __restrict__ dkeys, unsigned* __restrict__ gtab,
         ull* __restrict__ otab) {
    int b = blockIdx.x;                              // 16 blocks; b -> XCD b%8
    int t = threadIdx.x;

    __shared__ unsigned slen[NSEG_], spre[NSEG_];
    __shared__ unsigned sU;
    if (t < NSEG_) slen[t] = segcnt[b * NSEG_ + t];
    __syncthreads();
    if (t == 0) {
        unsigned acc = 0;
        for (int s = 0; s < NSEG_; ++s) { spre[s] = acc; acc += slen[s]; }
        sU = acc;
    }
    __syncthreads();
    int U = (int)sU;
    const ull* src = ckeys + (size_t)b * CKSTR_;
    ull* dk = dkeys + (size_t)b * CKSTR_;
    for (int s = 0; s < NSEG_; ++s) {
        unsigned L = slen[s], sb = spre[s];
        int base = segbase(s);
        for (unsigned i = t; i < L; i += 1024) dk[sb + i] = src[base + i];
    }
    __syncthreads();

    __shared__ unsigned hist[1024];
    __shared__ unsigned ss[1024];
    __shared__ ull skeys[K_];
    __shared__ ull spfx;
    __shared__ unsigned srem;
    __shared__ int ssel;

    ull thr = 0ull;
    if (U > K_) {
        ull prefix = 0ull;
        unsigned rem = (unsigned)K_;
        for (int sh = 40; sh >= 0; sh -= 10) {
            hist[t] = 0u;
            __syncthreads();
            ull hi = ~0ull << (sh + 10);
            for (int i = t; i < U; i += 1024) {
                ull k = dk[i];
                if ((k & hi) == prefix)
                    atomicAdd(&hist[(unsigned)(k >> sh) & 1023u], 1u);
            }
            __syncthreads();
            unsigned cc = hist[t];
            ss[t] = cc;
            __syncthreads();
            for (int off = 1; off < 1024; off <<= 1) {   // inclusive suffix sum
                unsigned v = (t + off < 1024) ? ss[t + off] : 0u;
                __syncthreads();
                ss[t] += v;
                __syncthreads();
            }
            unsigned Sincl = ss[t], Sexcl = Sincl - cc;
            if (Sexcl < rem && rem <= Sincl) {           // unique t (cc > 0)
                spfx = prefix | ((ull)t << sh);
                srem = rem - Sexcl;
            }
            __syncthreads();
            prefix = spfx;
            rem = srem;
            __syncthreads();
        }
        thr = prefix;                                    // exactly K_ keys >= thr
    }

    if (t == 0) ssel = 0;
    __syncthreads();
    for (int i = t; i < U; i += 1024) {
        ull k = dk[i];
        if (U <= K_ || k >= thr) { int p = atomicAdd(&ssel, 1); skeys[p] = k; }
    }
    __syncthreads();
    int S = ssel;                                        // ==256 when U>K, else ==U

    if (t < S) {
        // U>K: rank by full key desc (count desc, id asc). U<=K: id asc only.
        ull k = skeys[t];
        int rank = 0;
        if (U > K_) {
            for (int j = 0; j < S; ++j) rank += (skeys[j] > k);
        } else {
            unsigned kl = (unsigned)k;
            for (int j = 0; j < S; ++j) rank += ((unsigned)skeys[j] > kl);
        }
        unsigned u = ~((unsigned)k);
        int id = (int)(u ^ 0x80000000u);
        int idp = id + 32 * 10000 + 32 * 100 + 32;   // (vx+32)*1e4+(vy+32)*1e2+(vz+32)
        bool direct = false; int gidx = 0;
        if (idp >= 0) {
            int a = idp / 10000, r2 = idp % 10000, bb = r2 / 100, cc2 = r2 % 100;
            if (a < 64 && bb < 64 && cc2 < 64) { direct = true; gidx = (a << 12) | (bb << 6) | cc2; }
        }
        if (direct) {
            gtab[((size_t)b << 18) | gidx] = ~(unsigned)rank;
        } else {
            unsigned s2 = ohash(id);
            ull* tb = otab + (size_t)b * OC_;
            while ((unsigned)(tb[s2] >> 32) != u) s2 = (s2 + 1) & (OC_ - 1);
            tb[s2] = ((ull)u << 32) | (ull)(~(unsigned)rank);
        }
    }
}

__global__ void k_label(const int* __restrict__ pslot, const unsigned* __restrict__ gtab,
                        const ull* __restrict__ otab, int* __restrict__ out) {
    int b, chunk;
    swz(blockIdx.x, b, chunk);                       // grid == B_*N_/256
    int p = chunk * 256 + (int)threadIdx.x;
    size_t i = ((size_t)b << LOGN_) + (size_t)p;
    int s = __builtin_nontemporal_load(&pslot[i]);
    unsigned low;
    if (s >= 0) low = gtab[((size_t)b << 18) | s];
    else        low = (unsigned)otab[(size_t)b * OC_ + (s & (OC_ - 1))];
    __builtin_nontemporal_store((low >= 0xFFF00000u) ? (int)(~low) : -1, &out[i]);
}

extern "C" void kernel_launch(void* const* d_in, const int* in_sizes, int n_in,
                              void* d_out, int out_size, void* d_ws, size_t ws_size,
                              hipStream_t stream) {
    const float* coords = (const float*)d_in[0];
    int* out = (int*)d_out;

    // Workspace layout (~118 MB). gtab|otab contiguous -> one memset.
    char* w = (char*)d_ws;
    size_t off = 0;
    unsigned* gtab = (unsigned*)(w + off);      off += (size_t)B_ * G_ * 4;   // 16 MB
    ull* otab = (ull*)(w + off);                off += (size_t)B_ * OC_ * 8;  // 512 KB
    size_t zbytes = off;
    int* pslot = (int*)(w + off);               off += (size_t)B_ * N_ * 4;   // 16 MB
    ull* ckeys = (ull*)(w + off);               off += (size_t)B_ * CKSTR_ * 8; // 36.9 MB
    ull* dkeys = (ull*)(w + off);               off += (size_t)B_ * CKSTR_ * 8; // 36.9 MB
    unsigned* phist = (unsigned*)(w + off);     off += (size_t)B_ * BPB_ * WORDS_ * 4; // 11.2 MB
    unsigned* segcnt = (unsigned*)(w + off);    off += (size_t)B_ * NSEG_ * 4; // 11.2 KB

    hipMemsetAsync(gtab, 0, zbytes, stream);
    k_build<<<B_ * BPB_, 1024, 0, stream>>>(coords, gtab, otab, pslot, phist);
    k_compact<<<B_ * NSEG_, 256, 0, stream>>>(phist, gtab, otab, ckeys, segcnt);
    k_select<<<B_, 1024, 0, stream>>>(segcnt, ckeys, dkeys, gtab, otab);
    k_label<<<B_ * N_ / 256, 256, 0, stream>>>(pslot, gtab, otab, out);
}

// Round 12
// 93.628 us; speedup vs baseline: 2.2542x; 1.8189x over previous
//
#include <hip/hip_runtime.h>
#include <stdint.h>

// SuperpointGenerator: per-batch voxel id -> count -> top-256 by (count desc, id asc)
// -> labels 0..255 (else -1); if U<=256, label = dense rank by ascending id.
//
// Measured on gfx950 (R1..R11): any global RMW atomic is memory-side (~64B
// fabric round trip, ~150ns serialized per address, scope-independent). This
// version has ~zero contended global atomics:
//   - central 28^3 cube (98.5% of points) counted in per-block LDS u16-packed
//     histograms, flushed plain (phist); ring via sparse gtab atomicAdd;
//     far outliers via tiny CAS table otab.
//   - k_compact: segmented zero-atomic key emit (segcnt plain stores) + per-
//     block count-histogram (bin=min(count,1023)) flushed plain (bhist u16).
//   - k_pick: merge bhist -> per-batch count histogram; suffix scan gives the
//     selection threshold c* (Sexcl<K<=Sincl) and U. ONE pass (counts <= ~200,
//     so no 50-bit radix needed).
//   - k_gather: per-segment filter count>=c*; only blocks holding candidates
//     (~3/batch) issue one aggregated atomicAdd append.
//   - k_rank: rank candidates in LDS; rank<K wins; winner label = ~rank
//     (>= 0xFFFFFF00; decode low >= 0xFFF00000; counts never collide).
// XCD affinity: blocks of batch b have blockIdx%8 == b%8 (L2 heuristic only).

namespace {
constexpr int B_ = 16;
constexpr int N_ = 262144;            // 2^18 points per batch
constexpr int LOGN_ = 18;
constexpr int K_ = 256;
constexpr int G_ = 262144;            // 64^3 direct slots per batch
constexpr int OC_ = 4096;             // overflow CAS slots per batch
constexpr int DIM_ = 28, HDIM_ = 14;  // central LDS cube: voxels [-14,14)
constexpr int BINS_ = DIM_ * DIM_ * DIM_;   // 21952
constexpr int WORDS_ = BINS_ / 2;           // 10976 packed u32 words
constexpr int BPB_ = 16;              // build blocks per batch (256 total = 1/CU)
constexpr int PPB_ = N_ / BPB_;       // 16384 points per build block
// compact segments per batch: 43 central (cap 512) + 128 ring (cap 2048) + 4 otab (cap 1024)
constexpr int CSEG_ = 43, RSEG_ = 128, OSEG_ = 4;
constexpr int NSEG_ = CSEG_ + RSEG_ + OSEG_;           // 175
constexpr int RBASE_ = CSEG_ * 512;                    // 22016
constexpr int OBASE_ = RBASE_ + RSEG_ * 2048;          // 284160
constexpr int CKSTR_ = OBASE_ + OSEG_ * 1024;          // 288256 keys per batch
constexpr int CANDCAP_ = 8192;        // candidate cap per batch
typedef unsigned long long ull;
}

// bid -> (batch, chunk): batch = (bid&7) + 8*((bid>>3)&1)  => batch % 8 == bid % 8
__device__ __forceinline__ void swz(int bid, int& b, int& chunk) {
    b = (bid & 7) + (((bid >> 3) & 1) << 3);
    chunk = bid >> 4;
}

__device__ __forceinline__ unsigned ohash(int id) {
    return ((unsigned)id * 2654435761u) >> 20;       // 12-bit slot in otab
}

__device__ __forceinline__ int segbase(int s) {
    if (s < CSEG_) return s * 512;
    if (s < CSEG_ + RSEG_) return RBASE_ + (s - CSEG_) * 2048;
    return OBASE_ + (s - CSEG_ - RSEG_) * 1024;
}

__device__ __forceinline__ ull mkkey(unsigned cnt, int id) {
    return ((ull)cnt << 32) | (ull)(~((unsigned)id ^ 0x80000000u));
}

__global__ void __launch_bounds__(1024)
k_build(const float* __restrict__ coords, unsigned* __restrict__ gtab,
        ull* __restrict__ otab, int* __restrict__ pslot,
        unsigned* __restrict__ phist) {
    int b, chunk;
    swz(blockIdx.x, b, chunk);                       // grid == 256 (16 x 16)
    __shared__ unsigned lh[WORDS_];                  // 43.9 KB packed u16 pairs
    for (int w = threadIdx.x; w < WORDS_; w += 1024) lh[w] = 0u;
    __syncthreads();
    for (int r = 0; r < PPB_ / 1024; ++r) {
        int p = chunk * PPB_ + r * 1024 + (int)threadIdx.x;
        size_t i = ((size_t)b << LOGN_) + (size_t)p;
        const float* c = coords + i * 3;
        // Must match jnp.floor(c / 0.2f) bit-exactly: IEEE fp32 division.
        float cx = __builtin_nontemporal_load(c + 0);
        float cy = __builtin_nontemporal_load(c + 1);
        float cz = __builtin_nontemporal_load(c + 2);
        int vx = (int)floorf(cx / 0.2f);
        int vy = (int)floorf(cy / 0.2f);
        int vz = (int)floorf(cz / 0.2f);
        int ax = vx + HDIM_, ay = vy + HDIM_, az = vz + HDIM_;
        if ((unsigned)ax < (unsigned)DIM_ && (unsigned)ay < (unsigned)DIM_ &&
            (unsigned)az < (unsigned)DIM_) {
            int lidx = (ax * DIM_ + ay) * DIM_ + az;
            atomicAdd(&lh[lidx >> 1], 1u << ((lidx & 1) << 4));   // LDS, packed u16
            int gidx = ((vx + 32) << 12) | ((vy + 32) << 6) | (vz + 32);
            __builtin_nontemporal_store(gidx, &pslot[i]);
        } else if ((unsigned)(vx + 32) < 64u && (unsigned)(vy + 32) < 64u &&
                   (unsigned)(vz + 32) < 64u) {
            int gidx = ((vx + 32) << 12) | ((vy + 32) << 6) | (vz + 32);
            atomicAdd(&gtab[((size_t)b << 18) | gidx], 1u);       // ~1.5% of points
            __builtin_nontemporal_store(gidx, &pslot[i]);
        } else {                                     // essentially never; exact
            int id = vx * 10000 + vy * 100 + vz;
            unsigned u = (unsigned)id ^ 0x80000000u;
            unsigned s = ohash(id);
            ull* t = otab + (size_t)b * OC_;
            for (;;) {
                ull cur = t[s];
                if (cur == 0ull) {
                    ull prev = atomicCAS(&t[s], 0ull, ((ull)u << 32) | 1ull);
                    if (prev == 0ull) break;
                    cur = prev;
                }
                if ((unsigned)(cur >> 32) == u) { atomicAdd(&t[s], 1ull); break; }
                s = (s + 1) & (OC_ - 1);
            }
            __builtin_nontemporal_store((int)(0x80000000u | s), &pslot[i]);
        }
    }
    __syncthreads();
    unsigned* ph = phist + (size_t)(b * BPB_ + chunk) * WORDS_;
    for (int w = threadIdx.x; w < WORDS_; w += 1024)
        __builtin_nontemporal_store(lh[w], &ph[w]);  // plain coalesced flush
}

// One block = one segment. Emit keys (zero-atomic prefix append) + per-block
// count histogram flushed plain to bhist (u16 x 1024 per block).
__global__ void __launch_bounds__(256)
k_compact(const unsigned* __restrict__ phist, const unsigned* __restrict__ gtab,
          const ull* __restrict__ otab, ull* __restrict__ ckeys,
          unsigned* __restrict__ segcnt, unsigned short* __restrict__ bhist) {
    int b, chunk;
    swz(blockIdx.x, b, chunk);                       // grid == 16 * NSEG_
    __shared__ unsigned chist[1024];
    for (int d = threadIdx.x; d < 1024; d += 256) chist[d] = 0u;
    __syncthreads();

    int nv = 0;
    // --- per-thread item discovery (all static-indexed) ---
    unsigned s0 = 0, s1 = 0; int id0 = 0;            // central
    unsigned rc[8]; int rbase0 = 0;                  // ring counts
    ull e0 = 0, e1 = 0, e2 = 0, e3 = 0;              // otab entries
    if (chunk < CSEG_) {
        int w = chunk * 256 + (int)threadIdx.x;
        if (w < WORDS_) {
            const unsigned* ph = phist + (size_t)b * BPB_ * WORDS_ + w;
            #pragma unroll
            for (int blk = 0; blk < BPB_; ++blk) {
                unsigned v = ph[(size_t)blk * WORDS_];
                s0 += v & 0xFFFFu; s1 += v >> 16;
            }
            int bin0 = 2 * w;
            int ax = bin0 / (DIM_ * DIM_);
            int r2 = bin0 % (DIM_ * DIM_);
            int ay = r2 / DIM_, az = r2 % DIM_;
            id0 = (ax - HDIM_) * 10000 + (ay - HDIM_) * 100 + (az - HDIM_);
        }
        nv = (s0 != 0) + (s1 != 0);
        if (s0) atomicAdd(&chist[s0 < 1023u ? s0 : 1023u], 1u);
        if (s1) atomicAdd(&chist[s1 < 1023u ? s1 : 1023u], 1u);
    } else if (chunk < CSEG_ + RSEG_) {
        rbase0 = (chunk - CSEG_) * 2048 + (int)threadIdx.x * 8;
        const unsigned* gt = gtab + (((size_t)b << 18) + rbase0);
        uint4 c0 = *(const uint4*)gt;
        uint4 c1 = *(const uint4*)(gt + 4);
        rc[0] = c0.x; rc[1] = c0.y; rc[2] = c0.z; rc[3] = c0.w;
        rc[4] = c1.x; rc[5] = c1.y; rc[6] = c1.z; rc[7] = c1.w;
        #pragma unroll
        for (int j = 0; j < 8; ++j) {
            nv += (rc[j] != 0u);
            if (rc[j]) atomicAdd(&chist[rc[j] < 1023u ? rc[j] : 1023u], 1u);
        }
    } else {
        int s = (chunk - CSEG_ - RSEG_) * 1024 + (int)threadIdx.x * 4;
        const ull* ot = otab + (size_t)b * OC_ + s;
        e0 = ot[0]; e1 = ot[1]; e2 = ot[2]; e3 = ot[3];
        nv = (e0 != 0) + (e1 != 0) + (e2 != 0) + (e3 != 0);
        unsigned c;
        if (e0) { c = (unsigned)e0; atomicAdd(&chist[c < 1023u ? c : 1023u], 1u); }
        if (e1) { c = (unsigned)e1; atomicAdd(&chist[c < 1023u ? c : 1023u], 1u); }
        if (e2) { c = (unsigned)e2; atomicAdd(&chist[c < 1023u ? c : 1023u], 1u); }
        if (e3) { c = (unsigned)e3; atomicAdd(&chist[c < 1023u ? c : 1023u], 1u); }
    }

    // --- block-wide exclusive prefix of nv (shfl within wave, LDS across) ---
    int lane = threadIdx.x & 63, wave = threadIdx.x >> 6;
    unsigned pre = (unsigned)nv;
    #pragma unroll
    for (int o = 1; o < 64; o <<= 1) {
        unsigned v = __shfl_up(pre, o);
        if (lane >= o) pre += v;
    }
    __shared__ unsigned wtot[4], wbase[4];
    if (lane == 63) wtot[wave] = pre;
    __syncthreads();
    if (threadIdx.x == 0) {
        unsigned acc = 0;
        for (int w2 = 0; w2 < 4; ++w2) { wbase[w2] = acc; acc += wtot[w2]; }
        segcnt[b * NSEG_ + chunk] = acc;             // plain store, no atomic
    }
    __syncthreads();
    unsigned pos = wbase[wave] + pre - (unsigned)nv;

    // --- unrolled conditional writes (recompute keys; no indexed reg array) ---
    ull* dst = ckeys + (size_t)b * CKSTR_ + segbase(chunk);
    if (chunk < CSEG_) {
        if (s0) dst[pos++] = mkkey(s0, id0);
        if (s1) dst[pos]   = mkkey(s1, id0 + 1);
    } else if (chunk < CSEG_ + RSEG_) {
        #pragma unroll
        for (int j = 0; j < 8; ++j) {
            if (rc[j]) {
                int f = rbase0 + j;
                int id = ((f >> 12) - 32) * 10000 + (((f >> 6) & 63) - 32) * 100
                       + ((f & 63) - 32);
                dst[pos++] = mkkey(rc[j], id);
            }
        }
    } else {
        if (e0) dst[pos++] = ((ull)(unsigned)e0 << 32) | (ull)(~(unsigned)(e0 >> 32));
        if (e1) dst[pos++] = ((ull)(unsigned)e1 << 32) | (ull)(~(unsigned)(e1 >> 32));
        if (e2) dst[pos++] = ((ull)(unsigned)e2 << 32) | (ull)(~(unsigned)(e2 >> 32));
        if (e3) dst[pos]   = ((ull)(unsigned)e3 << 32) | (ull)(~(unsigned)(e3 >> 32));
    }

    // --- flush per-block count histogram (plain u16 stores) ---
    __syncthreads();
    unsigned short* bh = bhist + (((size_t)(b * NSEG_ + chunk)) << 10);
    for (int d = threadIdx.x; d < 1024; d += 256) {
        unsigned c = chist[d];
        bh[d] = (unsigned short)(c < 65535u ? c : 65535u);
    }
}

// One block per batch: merge block-hists, suffix scan -> c*, U.
__global__ void __launch_bounds__(1024)
k_pick(const unsigned short* __restrict__ bhist, unsigned* __restrict__ cstar,
       unsigned* __restrict__ uval) {
    int b = blockIdx.x, t = threadIdx.x;             // 16 blocks
    const unsigned short* bh = bhist + (((size_t)b * NSEG_) << 10) + t;
    unsigned h = 0;
    #pragma unroll 8
    for (int blk = 0; blk < NSEG_; ++blk) h += bh[(size_t)blk << 10];
    __shared__ unsigned ss[1024];
    __shared__ unsigned sc;
    ss[t] = h;
    __syncthreads();
    for (int off = 1; off < 1024; off <<= 1) {       // inclusive suffix sum
        unsigned v = (t + off < 1024) ? ss[t + off] : 0u;
        __syncthreads();
        ss[t] += v;
        __syncthreads();
    }
    unsigned U = ss[0];                              // bin 0 is always empty
    if (t == 0) sc = 0u;
    __syncthreads();
    if (U > (unsigned)K_) {
        unsigned Sincl = ss[t], Sexcl = Sincl - h;
        if (Sexcl < (unsigned)K_ && (unsigned)K_ <= Sincl) sc = (unsigned)t;  // unique
    }
    __syncthreads();
    if (t == 0) { cstar[b] = sc; uval[b] = U; }
}

// Filter each segment for count >= c*; append candidates (aggregated atomic,
// only the ~few blocks holding candidates issue one).
__global__ void __launch_bounds__(256)
k_gather(const unsigned* __restrict__ segcnt, const ull* __restrict__ ckeys,
         const unsigned* __restrict__ cstar, const unsigned* __restrict__ uval,
         ull* __restrict__ cand, unsigned* __restrict__ candcnt) {
    int b, chunk;
    swz(blockIdx.x, b, chunk);                       // grid == 16 * NSEG_
    unsigned L = segcnt[b * NSEG_ + chunk];
    if (L == 0) return;                              // block-uniform exit
    unsigned cmin = (uval[b] > (unsigned)K_) ? cstar[b] : 0u;
    const ull* src = ckeys + (size_t)b * CKSTR_ + segbase(chunk);
    __shared__ unsigned woff[4];
    __shared__ unsigned bbase;
    int iters = (int)((L + 255u) >> 8);
    for (int it = 0; it < iters; ++it) {
        int i = (it << 8) + (int)threadIdx.x;
        ull k = 0ull; bool valid = false;
        if (i < (int)L) { k = src[i]; valid = ((unsigned)(k >> 32) >= cmin); }
        ull mask = __ballot(valid);
        int lane = threadIdx.x & 63, wave = threadIdx.x >> 6;
        if (lane == 0) woff[wave] = (unsigned)__popcll(mask);
        __syncthreads();
        if (threadIdx.x == 0) {
            unsigned tot = 0;
            for (int w2 = 0; w2 < 4; ++w2) { unsigned c = woff[w2]; woff[w2] = tot; tot += c; }
            bbase = tot ? atomicAdd(&candcnt[b], tot) : 0u;
        }
        __syncthreads();
        if (valid) {
            unsigned pos = bbase + woff[wave]
                         + (unsigned)__popcll(mask & ((1ull << lane) - 1ull));
            if (pos < (unsigned)CANDCAP_) cand[((size_t)b << 13) + pos] = k;
        }
        __syncthreads();
    }
}

// Rank candidates; rank<K wins; write ~rank into gtab/otab label slots.
__global__ void __launch_bounds__(1024)
k_rank(const unsigned* __restrict__ candcnt, const ull* __restrict__ cand,
       const unsigned* __restrict__ uval, unsigned* __restrict__ gtab,
       ull* __restrict__ otab) {
    int b = blockIdx.x, t = threadIdx.x;             // 16 blocks
    unsigned cc = candcnt[b];
    int S = (int)(cc < (unsigned)CANDCAP_ ? cc : (unsigned)CANDCAP_);
    bool big = (uval[b] > (unsigned)K_);
    __shared__ ull sk[CANDCAP_];                     // 64 KB
    for (int i = t; i < S; i += 1024) sk[i] = cand[((size_t)b << 13) + i];
    __syncthreads();
    for (int idx = t; idx < S; idx += 1024) {
        ull k = sk[idx];
        int rank = 0;
        if (big) {
            for (int j = 0; j < S; ++j) rank += (sk[j] > k);       // (cnt desc, id asc)
        } else {
            unsigned kl = (unsigned)k;
            for (int j = 0; j < S; ++j) rank += ((unsigned)sk[j] > kl);  // id asc
        }
        if (rank < K_) {
            unsigned u = ~((unsigned)k);
            int id = (int)(u ^ 0x80000000u);
            int idp = id + 32 * 10000 + 32 * 100 + 32;
            bool direct = false; int gidx = 0;
            if (idp >= 0) {
                int a = idp / 10000, r2 = idp % 10000, bb = r2 / 100, cc2 = r2 % 100;
                if (a < 64 && bb < 64 && cc2 < 64) { direct = true; gidx = (a << 12) | (bb << 6) | cc2; }
            }
            if (direct) {
                gtab[((size_t)b << 18) | gidx] = ~(unsigned)rank;
            } else {
                unsigned s2 = ohash(id);
                ull* tb = otab + (size_t)b * OC_;
                while ((unsigned)(tb[s2] >> 32) != u) s2 = (s2 + 1) & (OC_ - 1);
                tb[s2] = ((ull)u << 32) | (ull)(~(unsigned)rank);
            }
        }
    }
}

__global__ void k_label(const int* __restrict__ pslot, const unsigned* __restrict__ gtab,
                        const ull* __restrict__ otab, int* __restrict__ out) {
    int b, chunk;
    swz(blockIdx.x, b, chunk);                       // grid == B_*N_/256
    int p = chunk * 256 + (int)threadIdx.x;
    size_t i = ((size_t)b << LOGN_) + (size_t)p;
    int s = __builtin_nontemporal_load(&pslot[i]);
    unsigned low;
    if (s >= 0) low = gtab[((size_t)b << 18) | s];
    else        low = (unsigned)otab[(size_t)b * OC_ + (s & (OC_ - 1))];
    __builtin_nontemporal_store((low >= 0xFFF00000u) ? (int)(~low) : -1, &out[i]);
}

extern "C" void kernel_launch(void* const* d_in, const int* in_sizes, int n_in,
                              void* d_out, int out_size, void* d_ws, size_t ws_size,
                              hipStream_t stream) {
    const float* coords = (const float*)d_in[0];
    int* out = (int*)d_out;

    // Workspace layout (~76 MB). gtab|otab|candcnt contiguous -> one memset.
    char* w = (char*)d_ws;
    size_t off = 0;
    unsigned* gtab = (unsigned*)(w + off);      off += (size_t)B_ * G_ * 4;   // 16 MB
    ull* otab = (ull*)(w + off);                off += (size_t)B_ * OC_ * 8;  // 512 KB
    unsigned* candcnt = (unsigned*)(w + off);   off += 64;                    // 64 B
    size_t zbytes = off;
    int* pslot = (int*)(w + off);               off += (size_t)B_ * N_ * 4;   // 16 MB
    ull* ckeys = (ull*)(w + off);               off += (size_t)B_ * CKSTR_ * 8; // 36.9 MB
    unsigned* phist = (unsigned*)(w + off);     off += (size_t)B_ * BPB_ * WORDS_ * 4; // 11.2 MB
    unsigned short* bhist = (unsigned short*)(w + off); off += (size_t)B_ * NSEG_ * 1024 * 2; // 5.7 MB
    unsigned* segcnt = (unsigned*)(w + off);    off += (size_t)B_ * NSEG_ * 4; // 11.2 KB
    unsigned* cstar = (unsigned*)(w + off);     off += B_ * 4;
    unsigned* uvalp = (unsigned*)(w + off);     off += B_ * 4;
    ull* cand = (ull*)(w + off);                off += (size_t)B_ * CANDCAP_ * 8; // 1 MB

    hipMemsetAsync(gtab, 0, zbytes, stream);
    k_build<<<B_ * BPB_, 1024, 0, stream>>>(coords, gtab, otab, pslot, phist);
    k_compact<<<B_ * NSEG_, 256, 0, stream>>>(phist, gtab, otab, ckeys, segcnt, bhist);
    k_pick<<<B_, 1024, 0, stream>>>(bhist, cstar, uvalp);
    k_gather<<<B_ * NSEG_, 256, 0, stream>>>(segcnt, ckeys, cstar, uvalp, cand, candcnt);
    k_rank<<<B_, 1024, 0, stream>>>(candcnt, cand, uvalp, gtab, otab);
    k_label<<<B_ * N_ / 256, 256, 0, stream>>>(pslot, gtab, otab, out);
}

// Round 14
// 82.634 us; speedup vs baseline: 2.5541x; 1.1330x over previous
//
#include <hip/hip_runtime.h>
#include <stdint.h>

// SuperpointGenerator: per-batch voxel id -> count -> top-256 by (count desc, id asc)
// -> labels 0..255 (else -1); if U<=256, label = dense rank by ascending id.
//
// Measured on gfx950 (R1..R12): any global RMW atomic is memory-side (~64B
// fabric round trip, ~150ns serialized per address). Design keeps global
// atomics to ~10^5 spread ops:
//   - central 28^3 cube (98.5% of points) counted in per-block LDS u16-packed
//     histograms, flushed plain (phist); ring via sparse gtab atomicAdd;
//     far outliers via tiny CAS table otab.
//   - k_compact: segmented zero-atomic key emit (segcnt plain stores); its
//     block count-histogram (bin=min(count,511)) merged into per-batch
//     ghist[512] via atomicAdd of NONZERO bins only.
//   - k_select2 (one block per batch): ghist suffix scan -> threshold c*, U;
//     wave-per-segment gather of count>=c* into LDS; rank; winner labels
//     written as ~rank (>= 0xFFFFFF00; decode low >= 0xFFF00000).
// XCD affinity: blocks of batch b have blockIdx%8 == b%8 (L2 heuristic only).
// NOTE: __builtin_nontemporal_* requires clang ext_vector_type, NOT HIP float4.

namespace {
constexpr int B_ = 16;
constexpr int N_ = 262144;            // 2^18 points per batch
constexpr int LOGN_ = 18;
constexpr int K_ = 256;
constexpr int G_ = 262144;            // 64^3 direct slots per batch
constexpr int OC_ = 4096;             // overflow CAS slots per batch
constexpr int DIM_ = 28, HDIM_ = 14;  // central LDS cube: voxels [-14,14)
constexpr int BINS_ = DIM_ * DIM_ * DIM_;   // 21952
constexpr int WORDS_ = BINS_ / 2;           // 10976 packed u32 words
constexpr int BPB_ = 16;              // build blocks per batch (256 total = 1/CU)
constexpr int PPB_ = N_ / BPB_;       // 16384 points per build block
// compact segments per batch: 43 central (cap 512) + 128 ring (cap 2048) + 4 otab (cap 1024)
constexpr int CSEG_ = 43, RSEG_ = 128, OSEG_ = 4;
constexpr int NSEG_ = CSEG_ + RSEG_ + OSEG_;           // 175
constexpr int RBASE_ = CSEG_ * 512;                    // 22016
constexpr int OBASE_ = RBASE_ + RSEG_ * 2048;          // 284160
constexpr int CKSTR_ = OBASE_ + OSEG_ * 1024;          // 288256 keys per batch
constexpr int CANDCAP_ = 8192;        // candidate cap per batch (LDS)
typedef unsigned long long ull;
typedef float  f32x4 __attribute__((ext_vector_type(4)));
typedef int    i32x4 __attribute__((ext_vector_type(4)));
}

// bid -> (batch, chunk): batch = (bid&7) + 8*((bid>>3)&1)  => batch % 8 == bid % 8
__device__ __forceinline__ void swz(int bid, int& b, int& chunk) {
    b = (bid & 7) + (((bid >> 3) & 1) << 3);
    chunk = bid >> 4;
}

__device__ __forceinline__ unsigned ohash(int id) {
    return ((unsigned)id * 2654435761u) >> 20;       // 12-bit slot in otab
}

__device__ __forceinline__ int segbase(int s) {
    if (s < CSEG_) return s * 512;
    if (s < CSEG_ + RSEG_) return RBASE_ + (s - CSEG_) * 2048;
    return OBASE_ + (s - CSEG_ - RSEG_) * 1024;
}

__device__ __forceinline__ ull mkkey(unsigned cnt, int id) {
    return ((ull)cnt << 32) | (ull)(~((unsigned)id ^ 0x80000000u));
}

// Classify one point: LDS-hist the central cube, gtab-atomic the ring,
// otab-CAS the far outliers. Returns the pslot code.
__device__ __forceinline__ int classify(float cx, float cy, float cz,
                                        unsigned* lh, unsigned* gtab_b,
                                        ull* otab_b) {
    // Must match jnp.floor(c / 0.2f) bit-exactly: IEEE fp32 division.
    int vx = (int)floorf(cx / 0.2f);
    int vy = (int)floorf(cy / 0.2f);
    int vz = (int)floorf(cz / 0.2f);
    int ax = vx + HDIM_, ay = vy + HDIM_, az = vz + HDIM_;
    if ((unsigned)ax < (unsigned)DIM_ && (unsigned)ay < (unsigned)DIM_ &&
        (unsigned)az < (unsigned)DIM_) {
        int lidx = (ax * DIM_ + ay) * DIM_ + az;
        atomicAdd(&lh[lidx >> 1], 1u << ((lidx & 1) << 4));   // LDS, packed u16
        return ((vx + 32) << 12) | ((vy + 32) << 6) | (vz + 32);
    }
    if ((unsigned)(vx + 32) < 64u && (unsigned)(vy + 32) < 64u &&
        (unsigned)(vz + 32) < 64u) {
        int gidx = ((vx + 32) << 12) | ((vy + 32) << 6) | (vz + 32);
        atomicAdd(&gtab_b[gidx], 1u);                         // ~1.5% of points
        return gidx;
    }
    int id = vx * 10000 + vy * 100 + vz;                      // essentially never
    unsigned u = (unsigned)id ^ 0x80000000u;
    unsigned s = ohash(id);
    for (;;) {
        ull cur = otab_b[s];
        if (cur == 0ull) {
            ull prev = atomicCAS(&otab_b[s], 0ull, ((ull)u << 32) | 1ull);
            if (prev == 0ull) break;
            cur = prev;
        }
        if ((unsigned)(cur >> 32) == u) { atomicAdd(&otab_b[s], 1ull); break; }
        s = (s + 1) & (OC_ - 1);
    }
    return (int)(0x80000000u | s);
}

__global__ void __launch_bounds__(1024)
k_build(const float* __restrict__ coords, unsigned* __restrict__ gtab,
        ull* __restrict__ otab, int* __restrict__ pslot,
        unsigned* __restrict__ phist) {
    int b, chunk;
    swz(blockIdx.x, b, chunk);                       // grid == 256 (16 x 16)
    __shared__ unsigned lh[WORDS_];                  // 43.9 KB packed u16 pairs
    for (int w = threadIdx.x; w < WORDS_; w += 1024) lh[w] = 0u;
    __syncthreads();
    unsigned* gtab_b = gtab + ((size_t)b << 18);
    ull* otab_b = otab + (size_t)b * OC_;
    for (int r = 0; r < PPB_ / 4096; ++r) {          // 4 points/thread/iter
        int p0 = chunk * PPB_ + r * 4096 + (int)threadIdx.x * 4;
        size_t i0 = ((size_t)b << LOGN_) + (size_t)p0;
        const f32x4* c4 = (const f32x4*)(coords + i0 * 3);  // 48 B, 16-aligned
        f32x4 a = __builtin_nontemporal_load(c4 + 0);
        f32x4 d = __builtin_nontemporal_load(c4 + 1);
        f32x4 e = __builtin_nontemporal_load(c4 + 2);
        i32x4 sv;
        sv.x = classify(a.x, a.y, a.z, lh, gtab_b, otab_b);
        sv.y = classify(a.w, d.x, d.y, lh, gtab_b, otab_b);
        sv.z = classify(d.z, d.w, e.x, lh, gtab_b, otab_b);
        sv.w = classify(e.y, e.z, e.w, lh, gtab_b, otab_b);
        __builtin_nontemporal_store(sv, (i32x4*)&pslot[i0]);
    }
    __syncthreads();
    unsigned* ph = phist + (size_t)(b * BPB_ + chunk) * WORDS_;
    for (int w = threadIdx.x; w < WORDS_; w += 1024)
        __builtin_nontemporal_store(lh[w], &ph[w]);  // plain coalesced flush
}

// One block = one segment. Emit keys (zero-atomic prefix append); merge the
// block's count-histogram into ghist[b][512] (nonzero bins only).
__global__ void __launch_bounds__(256)
k_compact(const unsigned* __restrict__ phist, const unsigned* __restrict__ gtab,
          const ull* __restrict__ otab, ull* __restrict__ ckeys,
          unsigned* __restrict__ segcnt, unsigned* __restrict__ ghist) {
    int b, chunk;
    swz(blockIdx.x, b, chunk);                       // grid == 16 * NSEG_
    __shared__ unsigned chist[512];
    for (int d = threadIdx.x; d < 512; d += 256) chist[d] = 0u;
    __syncthreads();

    int nv = 0;
    // --- per-thread item discovery (all static-indexed) ---
    unsigned s0 = 0, s1 = 0; int id0 = 0;            // central
    unsigned rc[8]; int rbase0 = 0;                  // ring counts
    ull e0 = 0, e1 = 0, e2 = 0, e3 = 0;              // otab entries
    if (chunk < CSEG_) {
        int w = chunk * 256 + (int)threadIdx.x;
        if (w < WORDS_) {
            const unsigned* ph = phist + (size_t)b * BPB_ * WORDS_ + w;
            #pragma unroll
            for (int blk = 0; blk < BPB_; ++blk) {
                unsigned v = ph[(size_t)blk * WORDS_];
                s0 += v & 0xFFFFu; s1 += v >> 16;
            }
            int bin0 = 2 * w;
            int ax = bin0 / (DIM_ * DIM_);
            int r2 = bin0 % (DIM_ * DIM_);
            int ay = r2 / DIM_, az = r2 % DIM_;
            id0 = (ax - HDIM_) * 10000 + (ay - HDIM_) * 100 + (az - HDIM_);
        }
        nv = (s0 != 0) + (s1 != 0);
        if (s0) atomicAdd(&chist[s0 < 511u ? s0 : 511u], 1u);
        if (s1) atomicAdd(&chist[s1 < 511u ? s1 : 511u], 1u);
    } else if (chunk < CSEG_ + RSEG_) {
        rbase0 = (chunk - CSEG_) * 2048 + (int)threadIdx.x * 8;
        const unsigned* gt = gtab + (((size_t)b << 18) + rbase0);
        uint4 c0 = *(const uint4*)gt;
        uint4 c1 = *(const uint4*)(gt + 4);
        rc[0] = c0.x; rc[1] = c0.y; rc[2] = c0.z; rc[3] = c0.w;
        rc[4] = c1.x; rc[5] = c1.y; rc[6] = c1.z; rc[7] = c1.w;
        #pragma unroll
        for (int j = 0; j < 8; ++j) {
            nv += (rc[j] != 0u);
            if (rc[j]) atomicAdd(&chist[rc[j] < 511u ? rc[j] : 511u], 1u);
        }
    } else {
        int s = (chunk - CSEG_ - RSEG_) * 1024 + (int)threadIdx.x * 4;
        const ull* ot = otab + (size_t)b * OC_ + s;
        e0 = ot[0]; e1 = ot[1]; e2 = ot[2]; e3 = ot[3];
        nv = (e0 != 0) + (e1 != 0) + (e2 != 0) + (e3 != 0);
        unsigned c;
        if (e0) { c = (unsigned)e0; atomicAdd(&chist[c < 511u ? c : 511u], 1u); }
        if (e1) { c = (unsigned)e1; atomicAdd(&chist[c < 511u ? c : 511u], 1u); }
        if (e2) { c = (unsigned)e2; atomicAdd(&chist[c < 511u ? c : 511u], 1u); }
        if (e3) { c = (unsigned)e3; atomicAdd(&chist[c < 511u ? c : 511u], 1u); }
    }

    // --- block-wide exclusive prefix of nv (shfl within wave, LDS across) ---
    int lane = threadIdx.x & 63, wave = threadIdx.x >> 6;
    unsigned pre = (unsigned)nv;
    #pragma unroll
    for (int o = 1; o < 64; o <<= 1) {
        unsigned v = __shfl_up(pre, o);
        if (lane >= o) pre += v;
    }
    __shared__ unsigned wtot[4], wbase[4];
    if (lane == 63) wtot[wave] = pre;
    __syncthreads();
    if (threadIdx.x == 0) {
        unsigned acc = 0;
        for (int w2 = 0; w2 < 4; ++w2) { wbase[w2] = acc; acc += wtot[w2]; }
        segcnt[b * NSEG_ + chunk] = acc;             // plain store, no atomic
    }
    __syncthreads();
    unsigned pos = wbase[wave] + pre - (unsigned)nv;

    // --- unrolled conditional writes (recompute keys; no indexed reg array) ---
    ull* dst = ckeys + (size_t)b * CKSTR_ + segbase(chunk);
    if (chunk < CSEG_) {
        if (s0) dst[pos++] = mkkey(s0, id0);
        if (s1) dst[pos]   = mkkey(s1, id0 + 1);
    } else if (chunk < CSEG_ + RSEG_) {
        #pragma unroll
        for (int j = 0; j < 8; ++j) {
            if (rc[j]) {
                int f = rbase0 + j;
                int id = ((f >> 12) - 32) * 10000 + (((f >> 6) & 63) - 32) * 100
                       + ((f & 63) - 32);
                dst[pos++] = mkkey(rc[j], id);
            }
        }
    } else {
        if (e0) dst[pos++] = ((ull)(unsigned)e0 << 32) | (ull)(~(unsigned)(e0 >> 32));
        if (e1) dst[pos++] = ((ull)(unsigned)e1 << 32) | (ull)(~(unsigned)(e1 >> 32));
        if (e2) dst[pos++] = ((ull)(unsigned)e2 << 32) | (ull)(~(unsigned)(e2 >> 32));
        if (e3) dst[pos]   = ((ull)(unsigned)e3 << 32) | (ull)(~(unsigned)(e3 >> 32));
    }

    // --- merge nonzero count-hist bins into per-batch ghist (sparse atomics) ---
    __syncthreads();
    for (int d = threadIdx.x; d < 512; d += 256) {
        unsigned c = chist[d];
        if (c) atomicAdd(&ghist[(b << 9) + d], c);
    }
}

// One block per batch: ghist scan -> c*,U; wave-per-segment gather; rank; write.
__global__ void __launch_bounds__(1024)
k_select2(const unsigned* __restrict__ ghist, const unsigned* __restrict__ segcnt,
          const ull* __restrict__ ckeys, unsigned* __restrict__ gtab,
          ull* __restrict__ otab) {
    int b = blockIdx.x, t = threadIdx.x;             // 16 blocks; b -> XCD b%8
    __shared__ unsigned ss[512];
    __shared__ unsigned slen[NSEG_];
    __shared__ ull sk[CANDCAP_];                     // 64 KB
    __shared__ unsigned sc;
    __shared__ int scnt;

    unsigned h = 0;
    if (t < 512) { h = ghist[(b << 9) + t]; ss[t] = h; }
    if (t < NSEG_) slen[t] = segcnt[b * NSEG_ + t];
    if (t == 0) { sc = 0u; scnt = 0; }
    __syncthreads();
    for (int off = 1; off < 512; off <<= 1) {        // inclusive suffix sum
        unsigned v = (t < 512 && t + off < 512) ? ss[t + off] : 0u;
        __syncthreads();
        if (t < 512) ss[t] += v;
        __syncthreads();
    }
    unsigned U = ss[0];                              // bin 0 always empty
    if (t < 512 && U > (unsigned)K_) {
        unsigned Sincl = ss[t], Sexcl = Sincl - h;
        if (Sexcl < (unsigned)K_ && (unsigned)K_ <= Sincl) sc = (unsigned)t;  // unique
    }
    __syncthreads();
    unsigned cmin = (U > (unsigned)K_) ? sc : 0u;

    // wave-per-segment gather of count >= cmin into LDS
    int lane = t & 63, wave = t >> 6;                // 16 waves
    const ull* keys = ckeys + (size_t)b * CKSTR_;
    for (int s = wave; s < NSEG_; s += 16) {
        unsigned L = slen[s];
        const ull* src = keys + segbase(s);
        for (int i = lane; i < (int)L; i += 64) {
            ull k = src[i];
            if ((unsigned)(k >> 32) >= cmin) {
                int p = atomicAdd(&scnt, 1);
                if (p < CANDCAP_) sk[p] = k;
            }
        }
    }
    __syncthreads();
    int S = scnt < CANDCAP_ ? scnt : CANDCAP_;       // ==Sincl(c*) when U>K, else U
    bool big = (U > (unsigned)K_);

    // rank candidates; rank<K wins; write ~rank labels
    for (int idx = t; idx < S; idx += 1024) {
        ull k = sk[idx];
        int rank = 0;
        if (big) {
            for (int j = 0; j < S; ++j) rank += (sk[j] > k);       // (cnt desc, id asc)
        } else {
            unsigned kl = (unsigned)k;
            for (int j = 0; j < S; ++j) rank += ((unsigned)sk[j] > kl);  // id asc
        }
        if (rank < K_) {
            unsigned u = ~((unsigned)k);
            int id = (int)(u ^ 0x80000000u);
            int idp = id + 32 * 10000 + 32 * 100 + 32;
            bool direct = false; int gidx = 0;
            if (idp >= 0) {
                int a = idp / 10000, r2 = idp % 10000, bb = r2 / 100, cc2 = r2 % 100;
                if (a < 64 && bb < 64 && cc2 < 64) { direct = true; gidx = (a << 12) | (bb << 6) | cc2; }
            }
            if (direct) {
                gtab[((size_t)b << 18) | gidx] = ~(unsigned)rank;
            } else {
                unsigned s2 = ohash(id);
                ull* tb = otab + (size_t)b * OC_;
                while ((unsigned)(tb[s2] >> 32) != u) s2 = (s2 + 1) & (OC_ - 1);
                tb[s2] = ((ull)u << 32) | (ull)(~(unsigned)rank);
            }
        }
    }
}

__global__ void __launch_bounds__(256)
k_label(const int* __restrict__ pslot, const unsigned* __restrict__ gtab,
        const ull* __restrict__ otab, int* __restrict__ out) {
    int b, chunk;
    swz(blockIdx.x, b, chunk);                       // grid == B_*N_/1024
    int p0 = chunk * 1024 + (int)threadIdx.x * 4;
    size_t i0 = ((size_t)b << LOGN_) + (size_t)p0;
    i32x4 s4 = __builtin_nontemporal_load((const i32x4*)&pslot[i0]);
    const unsigned* gt = gtab + ((size_t)b << 18);
    const ull* ot = otab + (size_t)b * OC_;
    i32x4 r;
    #pragma unroll
    for (int j = 0; j < 4; ++j) {
        int s = s4[j];
        unsigned low = (s >= 0) ? gt[s] : (unsigned)ot[s & (OC_ - 1)];
        r[j] = (low >= 0xFFF00000u) ? (int)(~low) : -1;
    }
    __builtin_nontemporal_store(r, (i32x4*)&out[i0]);
}

extern "C" void kernel_launch(void* const* d_in, const int* in_sizes, int n_in,
                              void* d_out, int out_size, void* d_ws, size_t ws_size,
                              hipStream_t stream) {
    const float* coords = (const float*)d_in[0];
    int* out = (int*)d_out;

    // Workspace layout (~81 MB). gtab|otab|ghist contiguous -> one memset.
    char* w = (char*)d_ws;
    size_t off = 0;
    unsigned* gtab = (unsigned*)(w + off);      off += (size_t)B_ * G_ * 4;   // 16 MB
    ull* otab = (ull*)(w + off);                off += (size_t)B_ * OC_ * 8;  // 512 KB
    unsigned* ghist = (unsigned*)(w + off);     off += (size_t)B_ * 512 * 4;  // 32 KB
    size_t zbytes = off;
    int* pslot = (int*)(w + off);               off += (size_t)B_ * N_ * 4;   // 16 MB
    ull* ckeys = (ull*)(w + off);               off += (size_t)B_ * CKSTR_ * 8; // 36.9 MB
    unsigned* phist = (unsigned*)(w + off);     off += (size_t)B_ * BPB_ * WORDS_ * 4; // 11.2 MB
    unsigned* segcnt = (unsigned*)(w + off);    off += (size_t)B_ * NSEG_ * 4; // 11.2 KB

    (void)hipMemsetAsync(gtab, 0, zbytes, stream);
    k_build<<<B_ * BPB_, 1024, 0, stream>>>(coords, gtab, otab, pslot, phist);
    k_compact<<<B_ * NSEG_, 256, 0, stream>>>(phist, gtab, otab, ckeys, segcnt, ghist);
    k_select2<<<B_, 1024, 0, stream>>>(ghist, segcnt, ckeys, gtab, otab);
    k_label<<<B_ * N_ / 1024, 256, 0, stream>>>(pslot, gtab, otab, out);
}

// Round 15
// 71.519 us; speedup vs baseline: 2.9511x; 1.1554x over previous
//
#include <hip/hip_runtime.h>
#include <stdint.h>

// SuperpointGenerator: per-batch voxel id -> count -> top-256 by (count desc, id asc)
// -> labels 0..255 (else -1); if U<=256, label = dense rank by ascending id.
//
// Measured on gfx950 (R1..R14): global RMW atomics are memory-side (~64B fabric
// round trip, ~150ns serialized per address). Design keeps them to ~10^4 spread:
//   - central 28^3 cube (98.5% of N(0,1)/0.2 points; data max |v|~28) counted in
//     per-block LDS u16-packed histograms, flushed plain (phist);
//   - ALL other points (~4K/batch) -> per-batch 16K-slot CAS hash (htab), keyed
//     by id (reproduces reference hash semantics exactly; id injective |v|<50);
//   - k_compact: zero-atomic segmented key emit (segcnt plain stores); block
//     count-histogram merged into ghist[512] (nonzero bins only);
//   - k_select2 (block/batch): ghist suffix scan -> c*,U; gather count>=c* into
//     LDS; rank; central winner labels -> ltab u16 (rank+1; 0 = none), hash
//     winners -> entry low32 = ~rank (>= 0xFFFFFF00);
//   - k_label: pslot u16 (lidx | 0x8000|slot) -> ltab (64KB/batch, cache-hot)
//     or htab; out int32.
// XCD affinity: blocks of batch b have blockIdx%8 == b%8 (L2 heuristic only).
// NOTE: __builtin_nontemporal_* requires clang ext_vector_type, NOT HIP float4.

namespace {
constexpr int B_ = 16;
constexpr int N_ = 262144;            // 2^18 points per batch
constexpr int LOGN_ = 18;
constexpr int K_ = 256;
constexpr int OC_ = 16384;            // hash slots per batch (~4K entries max)
constexpr int DIM_ = 28, HDIM_ = 14;  // central cube: voxels [-14,14)
constexpr int BINS_ = DIM_ * DIM_ * DIM_;   // 21952
constexpr int WORDS_ = BINS_ / 2;           // 10976 packed u32 words
constexpr int LTAB_ = 32768;          // direct label table entries per batch (u16)
constexpr int BPB_ = 16;              // build blocks per batch (256 total = 1/CU)
constexpr int PPB_ = N_ / BPB_;       // 16384 points per build block
// compact segments per batch: 43 central (cap 512) + 16 hash (cap 1024)
constexpr int CSEG_ = 43, HSEG_ = 16;
constexpr int NSEG_ = CSEG_ + HSEG_;                   // 59
constexpr int HBASE_ = CSEG_ * 512;                    // 22016
constexpr int CKSTR_ = HBASE_ + HSEG_ * 1024;          // 38400 keys per batch
constexpr int CANDCAP_ = 8192;        // candidate cap per batch (LDS)
typedef unsigned long long ull;
typedef float          f32x4 __attribute__((ext_vector_type(4)));
typedef unsigned short u16x4 __attribute__((ext_vector_type(4)));
}

// bid -> (batch, chunk): batch = (bid&7) + 8*((bid>>3)&1)  => batch % 8 == bid % 8
__device__ __forceinline__ void swz(int bid, int& b, int& chunk) {
    b = (bid & 7) + (((bid >> 3) & 1) << 3);
    chunk = bid >> 4;
}

__device__ __forceinline__ unsigned ohash(int id) {
    return ((unsigned)id * 2654435761u) >> 18;       // 14-bit slot in htab
}

__device__ __forceinline__ int segbase(int s) {
    return (s < CSEG_) ? s * 512 : HBASE_ + (s - CSEG_) * 1024;
}

__device__ __forceinline__ ull mkkey(unsigned cnt, int id) {
    return ((ull)cnt << 32) | (ull)(~((unsigned)id ^ 0x80000000u));
}

// Classify one point: LDS-hist the central cube, CAS-hash everything else.
// Returns the u16 pslot code (lidx, or 0x8000|slot).
__device__ __forceinline__ unsigned short classify(float cx, float cy, float cz,
                                                   unsigned* lh, ull* htab_b) {
    // Must match jnp.floor(c / 0.2f) bit-exactly: IEEE fp32 division.
    int vx = (int)floorf(cx / 0.2f);
    int vy = (int)floorf(cy / 0.2f);
    int vz = (int)floorf(cz / 0.2f);
    int ax = vx + HDIM_, ay = vy + HDIM_, az = vz + HDIM_;
    if ((unsigned)ax < (unsigned)DIM_ && (unsigned)ay < (unsigned)DIM_ &&
        (unsigned)az < (unsigned)DIM_) {
        int lidx = (ax * DIM_ + ay) * DIM_ + az;
        atomicAdd(&lh[lidx >> 1], 1u << ((lidx & 1) << 4));   // LDS, packed u16
        return (unsigned short)lidx;                          // < 21952
    }
    int id = vx * 10000 + vy * 100 + vz;                      // ~1.5% of points
    unsigned u = (unsigned)id ^ 0x80000000u;
    unsigned s = ohash(id);
    for (;;) {
        ull cur = htab_b[s];
        if (cur == 0ull) {
            ull prev = atomicCAS(&htab_b[s], 0ull, ((ull)u << 32) | 1ull);
            if (prev == 0ull) break;
            cur = prev;
        }
        if ((unsigned)(cur >> 32) == u) { atomicAdd(&htab_b[s], 1ull); break; }
        s = (s + 1) & (OC_ - 1);
    }
    return (unsigned short)(0x8000u | s);                     // slot < 16384
}

__global__ void __launch_bounds__(1024)
k_build(const float* __restrict__ coords, ull* __restrict__ htab,
        unsigned short* __restrict__ pslot, unsigned* __restrict__ phist) {
    int b, chunk;
    swz(blockIdx.x, b, chunk);                       // grid == 256 (16 x 16)
    __shared__ unsigned lh[WORDS_];                  // 43.9 KB packed u16 pairs
    for (int w = threadIdx.x; w < WORDS_; w += 1024) lh[w] = 0u;
    __syncthreads();
    ull* htab_b = htab + (size_t)b * OC_;
    for (int r = 0; r < PPB_ / 4096; ++r) {          // 4 points/thread/iter
        int p0 = chunk * PPB_ + r * 4096 + (int)threadIdx.x * 4;
        size_t i0 = ((size_t)b << LOGN_) + (size_t)p0;
        const f32x4* c4 = (const f32x4*)(coords + i0 * 3);  // 48 B, 16-aligned
        f32x4 a = __builtin_nontemporal_load(c4 + 0);
        f32x4 d = __builtin_nontemporal_load(c4 + 1);
        f32x4 e = __builtin_nontemporal_load(c4 + 2);
        u16x4 sv;
        sv.x = classify(a.x, a.y, a.z, lh, htab_b);
        sv.y = classify(a.w, d.x, d.y, lh, htab_b);
        sv.z = classify(d.z, d.w, e.x, lh, htab_b);
        sv.w = classify(e.y, e.z, e.w, lh, htab_b);
        __builtin_nontemporal_store(sv, (u16x4*)&pslot[i0]);
    }
    __syncthreads();
    unsigned* ph = phist + (size_t)(b * BPB_ + chunk) * WORDS_;
    for (int w = threadIdx.x; w < WORDS_; w += 1024)
        __builtin_nontemporal_store(lh[w], &ph[w]);  // plain coalesced flush
}

// One block = one segment. Emit keys (zero-atomic prefix append); merge the
// block's count-histogram into ghist[b][512] (nonzero bins only).
__global__ void __launch_bounds__(256)
k_compact(const unsigned* __restrict__ phist, const ull* __restrict__ htab,
          ull* __restrict__ ckeys, unsigned* __restrict__ segcnt,
          unsigned* __restrict__ ghist) {
    int b, chunk;
    swz(blockIdx.x, b, chunk);                       // grid == 16 * NSEG_ == 944
    __shared__ unsigned chist[512];
    for (int d = threadIdx.x; d < 512; d += 256) chist[d] = 0u;
    __syncthreads();

    int nv = 0;
    // --- per-thread item discovery (all static-indexed) ---
    unsigned s0 = 0, s1 = 0; int id0 = 0;            // central
    ull e0 = 0, e1 = 0, e2 = 0, e3 = 0;              // hash entries
    if (chunk < CSEG_) {
        int w = chunk * 256 + (int)threadIdx.x;
        if (w < WORDS_) {
            const unsigned* ph = phist + (size_t)b * BPB_ * WORDS_ + w;
            #pragma unroll
            for (int blk = 0; blk < BPB_; ++blk) {
                unsigned v = ph[(size_t)blk * WORDS_];
                s0 += v & 0xFFFFu; s1 += v >> 16;
            }
            int bin0 = 2 * w;
            int ax = bin0 / (DIM_ * DIM_);
            int r2 = bin0 % (DIM_ * DIM_);
            int ay = r2 / DIM_, az = r2 % DIM_;
            id0 = (ax - HDIM_) * 10000 + (ay - HDIM_) * 100 + (az - HDIM_);
        }
        nv = (s0 != 0) + (s1 != 0);
        if (s0) atomicAdd(&chist[s0 < 511u ? s0 : 511u], 1u);
        if (s1) atomicAdd(&chist[s1 < 511u ? s1 : 511u], 1u);
    } else {
        int s = (chunk - CSEG_) * 1024 + (int)threadIdx.x * 4;
        const ull* ot = htab + (size_t)b * OC_ + s;
        e0 = ot[0]; e1 = ot[1]; e2 = ot[2]; e3 = ot[3];
        nv = (e0 != 0) + (e1 != 0) + (e2 != 0) + (e3 != 0);
        unsigned c;
        if (e0) { c = (unsigned)e0; atomicAdd(&chist[c < 511u ? c : 511u], 1u); }
        if (e1) { c = (unsigned)e1; atomicAdd(&chist[c < 511u ? c : 511u], 1u); }
        if (e2) { c = (unsigned)e2; atomicAdd(&chist[c < 511u ? c : 511u], 1u); }
        if (e3) { c = (unsigned)e3; atomicAdd(&chist[c < 511u ? c : 511u], 1u); }
    }

    // --- block-wide exclusive prefix of nv (shfl within wave, LDS across) ---
    int lane = threadIdx.x & 63, wave = threadIdx.x >> 6;
    unsigned pre = (unsigned)nv;
    #pragma unroll
    for (int o = 1; o < 64; o <<= 1) {
        unsigned v = __shfl_up(pre, o);
        if (lane >= o) pre += v;
    }
    __shared__ unsigned wtot[4], wbase[4];
    if (lane == 63) wtot[wave] = pre;
    __syncthreads();
    if (threadIdx.x == 0) {
        unsigned acc = 0;
        for (int w2 = 0; w2 < 4; ++w2) { wbase[w2] = acc; acc += wtot[w2]; }
        segcnt[b * NSEG_ + chunk] = acc;             // plain store, no atomic
    }
    __syncthreads();
    unsigned pos = wbase[wave] + pre - (unsigned)nv;

    // --- unrolled conditional writes (recompute keys; no indexed reg array) ---
    ull* dst = ckeys + (size_t)b * CKSTR_ + segbase(chunk);
    if (chunk < CSEG_) {
        if (s0) dst[pos++] = mkkey(s0, id0);
        if (s1) dst[pos]   = mkkey(s1, id0 + 1);
    } else {
        if (e0) dst[pos++] = ((ull)(unsigned)e0 << 32) | (ull)(~(unsigned)(e0 >> 32));
        if (e1) dst[pos++] = ((ull)(unsigned)e1 << 32) | (ull)(~(unsigned)(e1 >> 32));
        if (e2) dst[pos++] = ((ull)(unsigned)e2 << 32) | (ull)(~(unsigned)(e2 >> 32));
        if (e3) dst[pos]   = ((ull)(unsigned)e3 << 32) | (ull)(~(unsigned)(e3 >> 32));
    }

    // --- merge nonzero count-hist bins into per-batch ghist (sparse atomics) ---
    __syncthreads();
    for (int d = threadIdx.x; d < 512; d += 256) {
        unsigned c = chist[d];
        if (c) atomicAdd(&ghist[(b << 9) + d], c);
    }
}

// One block per batch: ghist scan -> c*,U; gather; rank; write labels.
__global__ void __launch_bounds__(1024)
k_select2(const unsigned* __restrict__ ghist, const unsigned* __restrict__ segcnt,
          const ull* __restrict__ ckeys, unsigned short* __restrict__ ltab,
          ull* __restrict__ htab) {
    int b = blockIdx.x, t = threadIdx.x;             // 16 blocks; b -> XCD b%8
    __shared__ unsigned ss[512];
    __shared__ unsigned slen[NSEG_];
    __shared__ ull sk[CANDCAP_];                     // 64 KB
    __shared__ unsigned sc;
    __shared__ int scnt;

    unsigned h = 0;
    if (t < 512) { h = ghist[(b << 9) + t]; ss[t] = h; }
    if (t < NSEG_) slen[t] = segcnt[b * NSEG_ + t];
    if (t == 0) { sc = 0u; scnt = 0; }
    __syncthreads();
    for (int off = 1; off < 512; off <<= 1) {        // inclusive suffix sum
        unsigned v = (t < 512 && t + off < 512) ? ss[t + off] : 0u;
        __syncthreads();
        if (t < 512) ss[t] += v;
        __syncthreads();
    }
    unsigned U = ss[0];                              // bin 0 always empty
    if (t < 512 && U > (unsigned)K_) {
        unsigned Sincl = ss[t], Sexcl = Sincl - h;
        if (Sexcl < (unsigned)K_ && (unsigned)K_ <= Sincl) sc = (unsigned)t;  // unique
    }
    __syncthreads();
    unsigned cmin = (U > (unsigned)K_) ? sc : 0u;

    // wave-per-segment gather of count >= cmin into LDS
    int lane = t & 63, wave = t >> 6;                // 16 waves
    const ull* keys = ckeys + (size_t)b * CKSTR_;
    for (int s = wave; s < NSEG_; s += 16) {
        unsigned L = slen[s];
        const ull* src = keys + segbase(s);
        for (int i = lane; i < (int)L; i += 64) {
            ull k = src[i];
            if ((unsigned)(k >> 32) >= cmin) {
                int p = atomicAdd(&scnt, 1);
                if (p < CANDCAP_) sk[p] = k;
            }
        }
    }
    __syncthreads();
    int S = scnt < CANDCAP_ ? scnt : CANDCAP_;       // ==Sincl(c*) when U>K, else U
    bool big = (U > (unsigned)K_);

    // rank candidates; rank<K wins; write labels
    for (int idx = t; idx < S; idx += 1024) {
        ull k = sk[idx];
        int rank = 0;
        if (big) {
            for (int j = 0; j < S; ++j) rank += (sk[j] > k);       // (cnt desc, id asc)
        } else {
            unsigned kl = (unsigned)k;
            for (int j = 0; j < S; ++j) rank += ((unsigned)sk[j] > kl);  // id asc
        }
        if (rank < K_) {
            unsigned u = ~((unsigned)k);
            int id = (int)(u ^ 0x80000000u);
            // central iff id decodes to cube [-14,14)^3 (injective for data range)
            int idp = id + HDIM_ * 10000 + HDIM_ * 100 + HDIM_;
            bool central = false; int lidx = 0;
            if (idp >= 0) {
                int a = idp / 10000, r2 = idp % 10000, bb = r2 / 100, cc2 = r2 % 100;
                if (a < DIM_ && bb < DIM_ && cc2 < DIM_) {
                    central = true; lidx = (a * DIM_ + bb) * DIM_ + cc2;
                }
            }
            if (central) {
                ltab[((size_t)b << 15) + lidx] = (unsigned short)(rank + 1);  // 0 = none
            } else {
                unsigned s2 = ohash(id);
                ull* tb = htab + (size_t)b * OC_;
                while ((unsigned)(tb[s2] >> 32) != u) s2 = (s2 + 1) & (OC_ - 1);
                tb[s2] = ((ull)u << 32) | (ull)(~(unsigned)rank);
            }
        }
    }
}

__global__ void __launch_bounds__(256)
k_label(const unsigned short* __restrict__ pslot, const unsigned short* __restrict__ ltab,
        const ull* __restrict__ htab, int* __restrict__ out) {
    int b, chunk;
    swz(blockIdx.x, b, chunk);                       // grid == B_*N_/1024 == 4096
    int p0 = chunk * 1024 + (int)threadIdx.x * 4;
    size_t i0 = ((size_t)b << LOGN_) + (size_t)p0;
    u16x4 s4 = __builtin_nontemporal_load((const u16x4*)&pslot[i0]);
    const unsigned short* lt = ltab + ((size_t)b << 15);
    const ull* ht = htab + (size_t)b * OC_;
    typedef int i32x4 __attribute__((ext_vector_type(4)));
    i32x4 r;
    #pragma unroll
    for (int j = 0; j < 4; ++j) {
        unsigned s = s4[j];
        if (s < 0x8000u) {
            r[j] = (int)lt[s] - 1;                   // 0 = none -> -1
        } else {
            unsigned low = (unsigned)ht[s & (OC_ - 1)];
            r[j] = (low >= 0xFFF00000u) ? (int)(~low) : -1;
        }
    }
    __builtin_nontemporal_store(r, (i32x4*)&out[i0]);
}

extern "C" void kernel_launch(void* const* d_in, const int* in_sizes, int n_in,
                              void* d_out, int out_size, void* d_ws, size_t ws_size,
                              hipStream_t stream) {
    const float* coords = (const float*)d_in[0];
    int* out = (int*)d_out;

    // Workspace layout (~29 MB). htab|ltab|ghist contiguous -> one memset (~3MB).
    char* w = (char*)d_ws;
    size_t off = 0;
    ull* htab = (ull*)(w + off);                off += (size_t)B_ * OC_ * 8;  // 2 MB
    unsigned short* ltab = (unsigned short*)(w + off); off += (size_t)B_ * LTAB_ * 2; // 1 MB
    unsigned* ghist = (unsigned*)(w + off);     off += (size_t)B_ * 512 * 4;  // 32 KB
    size_t zbytes = off;
    unsigned short* pslot = (unsigned short*)(w + off); off += (size_t)B_ * N_ * 2; // 8 MB
    ull* ckeys = (ull*)(w + off);               off += (size_t)B_ * CKSTR_ * 8; // 4.9 MB
    unsigned* phist = (unsigned*)(w + off);     off += (size_t)B_ * BPB_ * WORDS_ * 4; // 11.2 MB
    unsigned* segcnt = (unsigned*)(w + off);    off += (size_t)B_ * NSEG_ * 4; // 3.8 KB

    (void)hipMemsetAsync(htab, 0, zbytes, stream);
    k_build<<<B_ * BPB_, 1024, 0, stream>>>(coords, htab, pslot, phist);
    k_compact<<<B_ * NSEG_, 256, 0, stream>>>(phist, htab, ckeys, segcnt, ghist);
    k_select2<<<B_, 1024, 0, stream>>>(ghist, segcnt, ckeys, ltab, htab);
    k_label<<<B_ * N_ / 1024, 256, 0, stream>>>(pslot, ltab, htab, out);
}